// Round 4
// baseline (1161.782 us; speedup 1.0000x reference)
//
#include <hip/hip_runtime.h>
#include <cstddef>
#include <cstdint>
#include <math.h>

#define Bsz   2
#define Sdim  2048
#define Hn    16
#define Ddim  1024
#define DEPTH 64
#define Mrows (Bsz * Sdim)
#define QTILES (Sdim / 64)
#define SZ    ((size_t)Bsz * Sdim * Ddim)   // 4,194,304 elements

typedef __attribute__((ext_vector_type(8))) short short8v;
typedef __attribute__((ext_vector_type(4))) short short4v;
typedef __attribute__((ext_vector_type(4))) float f32x4;

// ---------------------------------------------------------------------------
// fp32 -> (bf16 hi | bf16 lo) u32. hi = truncated top16 (exact);
// lo = RNE-bf16 of residual. hi+lo ~17 mantissa bits.
// ---------------------------------------------------------------------------
__device__ __forceinline__ uint32_t pack_hl(float x) {
    const uint32_t u  = __float_as_uint(x);
    const uint32_t hi = u & 0xFFFF0000u;
    const float    r  = x - __uint_as_float(hi);
    const uint32_t v  = __float_as_uint(r);
    const uint32_t lo = (v + 0x7FFFu + ((v >> 16) & 1u)) >> 16;
    return hi | lo;
}

// ---------------------------------------------------------------------------
// pack_x: fp32 X -> hi/lo bf16 planes (one conversion per element, ever)
// ---------------------------------------------------------------------------
__global__ __launch_bounds__(256) void pack_x_kernel(
    const float* __restrict__ X, short* __restrict__ hi, short* __restrict__ lo)
{
    const size_t i4 = (size_t)blockIdx.x * 256 + threadIdx.x;
    const float4 x = reinterpret_cast<const float4*>(X)[i4];
    const uint32_t p0 = pack_hl(x.x), p1 = pack_hl(x.y),
                   p2 = pack_hl(x.z), p3 = pack_hl(x.w);
    short4v h, l;
    h[0] = (short)(p0 >> 16); h[1] = (short)(p1 >> 16);
    h[2] = (short)(p2 >> 16); h[3] = (short)(p3 >> 16);
    l[0] = (short)(p0 & 0xFFFF); l[1] = (short)(p1 & 0xFFFF);
    l[2] = (short)(p2 & 0xFFFF); l[3] = (short)(p3 & 0xFFFF);
    reinterpret_cast<short4v*>(hi)[i4] = h;
    reinterpret_cast<short4v*>(lo)[i4] = l;
}

// ---------------------------------------------------------------------------
// pack_w: W[k][n] fp32 -> Whi[n][k], Wlo[n][k] bf16 planes (transposed)
// ---------------------------------------------------------------------------
__global__ __launch_bounds__(256) void pack_w_kernel(
    const float* __restrict__ W, short* __restrict__ Whi, short* __restrict__ Wlo)
{
    __shared__ uint32_t T[64][65];
    const int n0  = blockIdx.x * 64;
    const int k0  = blockIdx.y * 64;
    const int tid = threadIdx.x;
    const int c   = tid & 63;
    const int r0  = tid >> 6;
#pragma unroll
    for (int i = 0; i < 16; ++i) {
        const int kk = r0 * 16 + i;
        T[c][kk] = pack_hl(W[(size_t)(k0 + kk) * 1024 + n0 + c]);
    }
    __syncthreads();
#pragma unroll
    for (int i = 0; i < 16; ++i) {
        const int nn = r0 * 16 + i;
        const uint32_t t = T[nn][c];
        Whi[(size_t)(n0 + nn) * 1024 + k0 + c] = (short)(t >> 16);
        Wlo[(size_t)(n0 + nn) * 1024 + k0 + c] = (short)(t & 0xFFFF);
    }
}

// ---------------------------------------------------------------------------
// zero-fill (restores upper-triangle zeros in the scribbled attn region)
// ---------------------------------------------------------------------------
__global__ __launch_bounds__(256) void zero_kernel(float4* __restrict__ p)
{
    const size_t i = (size_t)blockIdx.x * 256 + threadIdx.x;
    p[i] = make_float4(0.f, 0.f, 0.f, 0.f);
}

// ---------------------------------------------------------------------------
// Split-bf16 plane GEMM: Y = X(4096,1024) @ W(1024,1024) + bias.
// 128x128 tile, 4 waves (2x2), BK=32. A planes via LDS [128][40]
// (16B-aligned rows, <=2-way banks); B planes direct from L2.
// Hot loop: 48 MFMA + 16 loads + addr VALU only (no pack/unpack).
// ---------------------------------------------------------------------------
template <bool SPLIT>
__device__ __forceinline__ void gemm_planes(
    const short* __restrict__ Xhi, const short* __restrict__ Xlo,
    const short* __restrict__ Whi, const short* __restrict__ Wlo,
    const float* __restrict__ bias,
    float* __restrict__ Y, short* __restrict__ Yhi, short* __restrict__ Ylo,
    float oscale)
{
    constexpr int K = 1024;
    __shared__ __align__(16) short Ahi[128][40];
    __shared__ __align__(16) short Alo[128][40];

    const int tid  = threadIdx.x;
    const int lane = tid & 63;
    const int wid  = tid >> 6;
    const int wr   = wid >> 1;
    const int wc   = wid & 1;
    const int l15  = lane & 15;
    const int lg   = lane >> 4;

    const int m0 = blockIdx.y * 128;
    const int n0 = blockIdx.x * 128;

    const int sr = tid >> 1;         // staging row 0..127
    const int sc = (tid & 1) * 16;   // staging col 0 / 16

    const short* wph[4]; const short* wpl[4];
#pragma unroll
    for (int fj = 0; fj < 4; ++fj) {
        const size_t row = (size_t)(n0 + wc * 64 + fj * 16 + l15) * K + lg * 8;
        wph[fj] = Whi + row;
        wpl[fj] = Wlo + row;
    }

    const size_t abase = (size_t)(m0 + sr) * K + sc;

    f32x4 acc[4][4] = {};

    for (int k0 = 0; k0 < K; k0 += 32) {
        // B fragments (global, L2-hot, no LDS dependency)
        short8v bh[4], bl[4];
#pragma unroll
        for (int fj = 0; fj < 4; ++fj) {
            bh[fj] = *reinterpret_cast<const short8v*>(wph[fj] + k0);
            bl[fj] = *reinterpret_cast<const short8v*>(wpl[fj] + k0);
        }

        // A staging loads
        const short8v xh0 = *reinterpret_cast<const short8v*>(Xhi + abase + k0);
        const short8v xh1 = *reinterpret_cast<const short8v*>(Xhi + abase + k0 + 8);
        const short8v xl0 = *reinterpret_cast<const short8v*>(Xlo + abase + k0);
        const short8v xl1 = *reinterpret_cast<const short8v*>(Xlo + abase + k0 + 8);

        __syncthreads();
        *reinterpret_cast<short8v*>(&Ahi[sr][sc])     = xh0;
        *reinterpret_cast<short8v*>(&Ahi[sr][sc + 8]) = xh1;
        *reinterpret_cast<short8v*>(&Alo[sr][sc])     = xl0;
        *reinterpret_cast<short8v*>(&Alo[sr][sc + 8]) = xl1;
        __syncthreads();

#pragma unroll
        for (int fi = 0; fi < 4; ++fi) {
            const int ar = wr * 64 + fi * 16 + l15;
            const short8v ah = *reinterpret_cast<const short8v*>(&Ahi[ar][lg * 8]);
            const short8v al = *reinterpret_cast<const short8v*>(&Alo[ar][lg * 8]);
#pragma unroll
            for (int fj = 0; fj < 4; ++fj) {
                acc[fi][fj] = __builtin_amdgcn_mfma_f32_16x16x32_bf16(
                    ah, bh[fj], acc[fi][fj], 0, 0, 0);
                acc[fi][fj] = __builtin_amdgcn_mfma_f32_16x16x32_bf16(
                    ah, bl[fj], acc[fi][fj], 0, 0, 0);
                acc[fi][fj] = __builtin_amdgcn_mfma_f32_16x16x32_bf16(
                    al, bh[fj], acc[fi][fj], 0, 0, 0);
            }
        }
    }

#pragma unroll
    for (int fj = 0; fj < 4; ++fj) {
        const int col = n0 + wc * 64 + fj * 16 + l15;
        const float bv = bias[col];
#pragma unroll
        for (int fi = 0; fi < 4; ++fi) {
#pragma unroll
            for (int j = 0; j < 4; ++j) {
                const int row = m0 + wr * 64 + fi * 16 + lg * 4 + j;
                const float val = (acc[fi][fj][j] + bv) * oscale;
                if (SPLIT) {
                    const int bb = row >> 11;
                    const int ss = row & 2047;
                    const int hh = col >> 6;
                    const int dd = col & 63;
                    const size_t idx =
                        (((size_t)bb * Hn + hh) * Sdim + ss) * DEPTH + dd;
                    const uint32_t p = pack_hl(val);
                    Yhi[idx] = (short)(p >> 16);
                    Ylo[idx] = (short)(p & 0xFFFF);
                } else {
                    Y[(size_t)row * Ddim + col] = val;
                }
            }
        }
    }
}

__global__ __launch_bounds__(256) void proj_kernel(
    const short* __restrict__ XqH, const short* __restrict__ XqL,
    const short* __restrict__ XkH, const short* __restrict__ XkL,
    const short* __restrict__ XvH, const short* __restrict__ XvL,
    const short* __restrict__ WqH, const short* __restrict__ WqL,
    const short* __restrict__ WkH, const short* __restrict__ WkL,
    const short* __restrict__ WvH, const short* __restrict__ WvL,
    const float* __restrict__ bq, const float* __restrict__ bk,
    const float* __restrict__ bv,
    short* __restrict__ qhH, short* __restrict__ qhL,
    short* __restrict__ khH, short* __restrict__ khL,
    short* __restrict__ vhH, short* __restrict__ vhL)
{
    const short *Xh, *Xl, *Wh, *Wl; const float* bias; short *Yh, *Yl;
    float sc = 1.0f;
    switch (blockIdx.z) {
        case 0:  Xh=XqH; Xl=XqL; Wh=WqH; Wl=WqL; bias=bq; Yh=qhH; Yl=qhL; sc=0.125f; break;
        case 1:  Xh=XkH; Xl=XkL; Wh=WkH; Wl=WkL; bias=bk; Yh=khH; Yl=khL; break;
        default: Xh=XvH; Xl=XvL; Wh=WvH; Wl=WvL; bias=bv; Yh=vhH; Yl=vhL; break;
    }
    gemm_planes<true>(Xh, Xl, Wh, Wl, bias, nullptr, Yh, Yl, sc);
}

__global__ __launch_bounds__(256) void oproj_kernel(
    const short* __restrict__ ctxH, const short* __restrict__ ctxL,
    const short* __restrict__ WoH, const short* __restrict__ WoL,
    const float* __restrict__ bo, float* __restrict__ out)
{
    gemm_planes<false>(ctxH, ctxL, WoH, WoL, bo, out, nullptr, nullptr, 1.0f);
}

// ---------------------------------------------------------------------------
// MFMA attention, plane operands. One block (4 waves) per 64-row Q-tile per
// (b,h). Q frags hoisted (pre-scaled 1/8); K frags direct from L2 (plane
// loads, zero unpack). Pass 1: QK^T + online max/sum. Pass 2: QK^T, p =
// exp(l-m)/s, attn stores, P/V planes -> LDS [64][72] (16B rows, 2-way
// banks), PV MFMA. XCD-chunked mapping keeps each (b,h)'s K/V L2-resident.
// ---------------------------------------------------------------------------
__device__ __forceinline__ void qk_tile_pl(const short* __restrict__ kH,
                                           const short* __restrict__ kL,
                                           int k0, int l15, int lg,
                                           const short8v* qhi, const short8v* qlo,
                                           f32x4* sacc)
{
#pragma unroll
    for (int fc = 0; fc < 4; ++fc) {
        const size_t ro = (size_t)(k0 + fc * 16 + l15) * DEPTH + lg * 8;
#pragma unroll
        for (int kk = 0; kk < 2; ++kk) {
            const short8v khi = *reinterpret_cast<const short8v*>(kH + ro + kk * 32);
            const short8v klo = *reinterpret_cast<const short8v*>(kL + ro + kk * 32);
            sacc[fc] = __builtin_amdgcn_mfma_f32_16x16x32_bf16(qhi[kk], khi, sacc[fc], 0, 0, 0);
            sacc[fc] = __builtin_amdgcn_mfma_f32_16x16x32_bf16(qhi[kk], klo, sacc[fc], 0, 0, 0);
            sacc[fc] = __builtin_amdgcn_mfma_f32_16x16x32_bf16(qlo[kk], khi, sacc[fc], 0, 0, 0);
        }
    }
}

__global__ __launch_bounds__(256) void attn_mfma_kernel(
    const short* __restrict__ qH, const short* __restrict__ qL,
    const short* __restrict__ kH, const short* __restrict__ kL,
    const short* __restrict__ vH, const short* __restrict__ vL,
    float* __restrict__ attn, short* __restrict__ ctxH, short* __restrict__ ctxL)
{
    __shared__ __align__(16) short Vth[64][72];
    __shared__ __align__(16) short Vtl[64][72];
    __shared__ __align__(16) short Psh[64][72];
    __shared__ __align__(16) short Psl[64][72];

    const int n   = blockIdx.x;
    const int xcd = n & 7;
    const int s   = n >> 3;
    const int c   = ((s >> 5) << 3) | xcd;    // (b,h) combo
    const int qt  = 31 - (s & 31);            // heavy tiles first
    const int b   = c >> 4;
    const int h   = c & 15;

    const int tid  = threadIdx.x;
    const int lane = tid & 63;
    const int wid  = tid >> 6;
    const int l15  = lane & 15;
    const int lg   = lane >> 4;

    const size_t head = ((size_t)(b * Hn + h)) * Sdim * DEPTH;
    const int q0 = qt * 64;

    const short* khh = kH + head;
    const short* khl = kL + head;
    const short* vhh = vH + head;
    const short* vhl = vL + head;

    // Q fragments hoisted
    short8v qhi[2], qlo[2];
    {
        const size_t qo = head + (size_t)(q0 + wid * 16 + l15) * DEPTH + lg * 8;
#pragma unroll
        for (int kk = 0; kk < 2; ++kk) {
            qhi[kk] = *reinterpret_cast<const short8v*>(qH + qo + kk * 32);
            qlo[kk] = *reinterpret_cast<const short8v*>(qL + qo + kk * 32);
        }
    }

    float m_r[4], s_r[4];
#pragma unroll
    for (int j = 0; j < 4; ++j) { m_r[j] = -INFINITY; s_r[j] = 0.f; }

    // ---------------- pass 1: stats (no LDS, no barriers) ----------------
    for (int kt = 0; kt <= qt; ++kt) {
        const int k0 = kt * 64;
        f32x4 sacc[4] = {};
        qk_tile_pl(khh, khl, k0, l15, lg, qhi, qlo, sacc);

        const bool diag = (kt == qt);
#pragma unroll
        for (int j = 0; j < 4; ++j) {
            const int qg = q0 + wid * 16 + lg * 4 + j;
            float v0 = sacc[0][j], v1 = sacc[1][j], v2 = sacc[2][j], v3 = sacc[3][j];
            if (diag) {
                if (k0 +  0 + l15 > qg) v0 = -INFINITY;
                if (k0 + 16 + l15 > qg) v1 = -INFINITY;
                if (k0 + 32 + l15 > qg) v2 = -INFINITY;
                if (k0 + 48 + l15 > qg) v3 = -INFINITY;
            }
            float tmax = fmaxf(fmaxf(v0, v1), fmaxf(v2, v3));
            tmax = fmaxf(tmax, __shfl_xor(tmax, 1, 64));
            tmax = fmaxf(tmax, __shfl_xor(tmax, 2, 64));
            tmax = fmaxf(tmax, __shfl_xor(tmax, 4, 64));
            tmax = fmaxf(tmax, __shfl_xor(tmax, 8, 64));

            const float mnew = fmaxf(m_r[j], tmax);
            float ps = __expf(v0 - mnew) + __expf(v1 - mnew) +
                       __expf(v2 - mnew) + __expf(v3 - mnew);
            ps += __shfl_xor(ps, 1, 64);
            ps += __shfl_xor(ps, 2, 64);
            ps += __shfl_xor(ps, 4, 64);
            ps += __shfl_xor(ps, 8, 64);

            s_r[j] = s_r[j] * __expf(m_r[j] - mnew) + ps;
            m_r[j] = mnew;
        }
    }

    float inv_s[4];
#pragma unroll
    for (int j = 0; j < 4; ++j) inv_s[j] = 1.f / s_r[j];

    f32x4 cacc[4] = {};

    const int vr = tid >> 2;        // V staging: row 0..63
    const int vq = tid & 3;

    // ---------------- pass 2: attn write + PV ----------------
    for (int kt = 0; kt <= qt; ++kt) {
        const int k0 = kt * 64;

        // V staging loads (issue before compute)
        const size_t vo = (size_t)(k0 + vr) * DEPTH + vq * 16;
        const short8v vh0 = *reinterpret_cast<const short8v*>(vhh + vo);
        const short8v vh1 = *reinterpret_cast<const short8v*>(vhh + vo + 8);
        const short8v vl0 = *reinterpret_cast<const short8v*>(vhl + vo);
        const short8v vl1 = *reinterpret_cast<const short8v*>(vhl + vo + 8);

        f32x4 sacc[4] = {};
        qk_tile_pl(khh, khl, k0, l15, lg, qhi, qlo, sacc);

        const bool diag = (kt == qt);
        uint32_t ppk[4][4];
#pragma unroll
        for (int j = 0; j < 4; ++j) {
            const int qg = q0 + wid * 16 + lg * 4 + j;
            float* arow = attn + ((size_t)(b * Hn + h) * Sdim + qg) * Sdim;
#pragma unroll
            for (int fc = 0; fc < 4; ++fc) {
                const int col = k0 + fc * 16 + l15;
                float p = __expf(sacc[fc][j] - m_r[j]) * inv_s[j];
                if (diag && col > qg) p = 0.f;
                arow[col] = p;
                ppk[fc][j] = pack_hl(p);
            }
        }

        __syncthreads();   // prior PV reads done

        // stage V transposed planes
#pragma unroll
        for (int t = 0; t < 8; ++t) {
            Vth[vq * 16 + t][vr]     = vh0[t];
            Vth[vq * 16 + 8 + t][vr] = vh1[t];
            Vtl[vq * 16 + t][vr]     = vl0[t];
            Vtl[vq * 16 + 8 + t][vr] = vl1[t];
        }
        // stage P planes [qrow][key]
#pragma unroll
        for (int j = 0; j < 4; ++j)
#pragma unroll
            for (int fc = 0; fc < 4; ++fc) {
                const uint32_t p = ppk[fc][j];
                Psh[wid * 16 + lg * 4 + j][fc * 16 + l15] = (short)(p >> 16);
                Psl[wid * 16 + lg * 4 + j][fc * 16 + l15] = (short)(p & 0xFFFF);
            }
        __syncthreads();

        // PV
#pragma unroll
        for (int kk = 0; kk < 2; ++kk) {
            const short8v ph = *reinterpret_cast<const short8v*>(
                &Psh[wid * 16 + l15][kk * 32 + lg * 8]);
            const short8v pl = *reinterpret_cast<const short8v*>(
                &Psl[wid * 16 + l15][kk * 32 + lg * 8]);
#pragma unroll
            for (int fc = 0; fc < 4; ++fc) {
                const short8v vh = *reinterpret_cast<const short8v*>(
                    &Vth[fc * 16 + l15][kk * 32 + lg * 8]);
                const short8v vl = *reinterpret_cast<const short8v*>(
                    &Vtl[fc * 16 + l15][kk * 32 + lg * 8]);
                cacc[fc] = __builtin_amdgcn_mfma_f32_16x16x32_bf16(ph, vh, cacc[fc], 0, 0, 0);
                cacc[fc] = __builtin_amdgcn_mfma_f32_16x16x32_bf16(ph, vl, cacc[fc], 0, 0, 0);
                cacc[fc] = __builtin_amdgcn_mfma_f32_16x16x32_bf16(pl, vh, cacc[fc], 0, 0, 0);
            }
        }
    }

    // ctx planes in concat layout (B, S, D)
#pragma unroll
    for (int fc = 0; fc < 4; ++fc)
#pragma unroll
        for (int j = 0; j < 4; ++j) {
            const int qg = q0 + wid * 16 + lg * 4 + j;
            const size_t idx =
                ((size_t)b * Sdim + qg) * Ddim + h * DEPTH + fc * 16 + l15;
            const uint32_t p = pack_hl(cacc[fc][j]);
            ctxH[idx] = (short)(p >> 16);
            ctxL[idx] = (short)(p & 0xFFFF);
        }
}

// ---------------------------------------------------------------------------
extern "C" void kernel_launch(void* const* d_in, const int* in_sizes, int n_in,
                              void* d_out, int out_size, void* d_ws, size_t ws_size,
                              hipStream_t stream)
{
    (void)in_sizes; (void)n_in; (void)out_size; (void)ws_size;

    const float* v  = (const float*)d_in[0];
    const float* k  = (const float*)d_in[1];
    const float* q  = (const float*)d_in[2];
    const float* Wq = (const float*)d_in[4];
    const float* bq = (const float*)d_in[5];
    const float* Wk = (const float*)d_in[6];
    const float* bk = (const float*)d_in[7];
    const float* Wv = (const float*)d_in[8];
    const float* bv = (const float*)d_in[9];
    const float* Wo = (const float*)d_in[10];
    const float* bo = (const float*)d_in[11];

    float* out  = (float*)d_out;
    float* attn = out + SZ;

    // --- ws layout (shorts): qkv planes, ctx planes, Wo planes = ~71 MB ---
    short* w = (short*)d_ws;
    short* qhH = w;            short* qhL = qhH + SZ;
    short* khH = qhL + SZ;     short* khL = khH + SZ;
    short* vhH = khL + SZ;     short* vhL = vhH + SZ;
    short* ctxH = vhL + SZ;    short* ctxL = ctxH + SZ;
    short* WoH = ctxL + SZ;    short* WoL = WoH + 1024 * 1024;

    // --- scribble scratch inside the (not yet written) attn output region:
    //     X planes (50 MB) + Wq/Wk/Wv planes (12.6 MB); zeroed before attn ---
    short* sc = (short*)attn;
    short* XqH = sc;           short* XqL = XqH + SZ;
    short* XkH = XqL + SZ;     short* XkL = XkH + SZ;
    short* XvH = XkL + SZ;     short* XvL = XvH + SZ;
    short* WqH = XvL + SZ;     short* WqL = WqH + 1024 * 1024;
    short* WkH = WqL + 1024 * 1024;  short* WkL = WkH + 1024 * 1024;
    short* WvH = WkL + 1024 * 1024;  short* WvL = WvH + 1024 * 1024;
    // scribble extent: 6*SZ + 6*1M shorts = 62,914,560 B = 3,932,160 float4s

    dim3 gpk(16, 16);
    pack_w_kernel<<<gpk, 256, 0, stream>>>(Wq, WqH, WqL);
    pack_w_kernel<<<gpk, 256, 0, stream>>>(Wk, WkH, WkL);
    pack_w_kernel<<<gpk, 256, 0, stream>>>(Wv, WvH, WvL);
    pack_w_kernel<<<gpk, 256, 0, stream>>>(Wo, WoH, WoL);

    pack_x_kernel<<<4096, 256, 0, stream>>>(q, XqH, XqL);
    pack_x_kernel<<<4096, 256, 0, stream>>>(k, XkH, XkL);
    pack_x_kernel<<<4096, 256, 0, stream>>>(v, XvH, XvL);

    dim3 gproj(Ddim / 128, Mrows / 128, 3);
    proj_kernel<<<gproj, 256, 0, stream>>>(XqH, XqL, XkH, XkL, XvH, XvL,
                                           WqH, WqL, WkH, WkL, WvH, WvL,
                                           bq, bk, bv,
                                           qhH, qhL, khH, khL, vhH, vhL);

    zero_kernel<<<15360, 256, 0, stream>>>((float4*)attn);

    attn_mfma_kernel<<<dim3(QTILES * Hn * Bsz), 256, 0, stream>>>(
        qhH, qhL, khH, khL, vhH, vhL, attn, ctxH, ctxL);

    dim3 gout(Ddim / 128, Mrows / 128);
    oproj_kernel<<<gout, 256, 0, stream>>>(ctxH, ctxL, WoH, WoL, bo, out);
}

// Round 7
// 1113.385 us; speedup vs baseline: 1.0435x; 1.0435x over previous
//
#include <hip/hip_runtime.h>
#include <cstddef>
#include <cstdint>
#include <math.h>

#define Bsz   2
#define Sdim  2048
#define Hn    16
#define Ddim  1024
#define DEPTH 64
#define Mrows (Bsz * Sdim)
#define QTILES (Sdim / 64)

typedef __attribute__((ext_vector_type(8))) short short8v;
typedef __attribute__((ext_vector_type(4))) float f32x4;

// ---------------------------------------------------------------------------
// fp32 -> packed (bf16 hi | bf16 lo) in one u32.
// hi = truncated top 16 bits (exact); lo = RNE-bf16 of the residual.
// hi+lo carries ~17 mantissa bits -> split-bf16 GEMM error ~1e-4 relative.
// ---------------------------------------------------------------------------
__device__ __forceinline__ uint32_t pack_hl(float x) {
    const uint32_t u  = __float_as_uint(x);
    const uint32_t hi = u & 0xFFFF0000u;
    const float    r  = x - __uint_as_float(hi);
    const uint32_t v  = __float_as_uint(r);
    const uint32_t lo = (v + 0x7FFFu + ((v >> 16) & 1u)) >> 16;
    return hi | lo;
}

// unpack 8 packed elems (2x uint4) into hi / lo bf16 fragments (short8).
// unit q of the fragment holds elems (2q, 2q+1): elem 2q in bits[15:0].
// Same slot->k bijection used for ALL A and B fragments -> cancels in MFMA.
__device__ __forceinline__ void unpack_frag(const uint4& r0, const uint4& r1,
                                            short8v& hi, short8v& lo)
{
    union { uint32_t u[4]; short8v v; } H, L;
    const uint32_t p[8] = {r0.x, r0.y, r0.z, r0.w, r1.x, r1.y, r1.z, r1.w};
#pragma unroll
    for (int q = 0; q < 4; ++q) {
        const uint32_t p0 = p[2 * q], p1 = p[2 * q + 1];
        H.u[q] = (p0 >> 16) | (p1 & 0xFFFF0000u);
        L.u[q] = (p0 & 0xFFFFu) | (p1 << 16);
    }
    hi = H.v; lo = L.v;
}

// ---------------------------------------------------------------------------
// Pack + transpose a 1024x1024 weight: Wt[n][k] = pack_hl(W[k][n]).
// ---------------------------------------------------------------------------
__device__ __forceinline__ void pack_w_body(const float* __restrict__ W,
                                            uint32_t* __restrict__ Wt)
{
    __shared__ uint32_t T[64][65];
    const int n0  = blockIdx.x * 64;
    const int k0  = blockIdx.y * 64;
    const int tid = threadIdx.x;
    const int c   = tid & 63;
    const int r0  = tid >> 6;
#pragma unroll
    for (int i = 0; i < 16; ++i) {
        const int kk = r0 * 16 + i;
        T[c][kk] = pack_hl(W[(size_t)(k0 + kk) * 1024 + n0 + c]);
    }
    __syncthreads();
#pragma unroll
    for (int i = 0; i < 16; ++i) {
        const int nn = r0 * 16 + i;
        Wt[(size_t)(n0 + nn) * 1024 + k0 + c] = T[nn][c];
    }
}

__global__ __launch_bounds__(256) void pack_w_kernel(const float* __restrict__ W,
                                                     uint32_t* __restrict__ Wt)
{
    pack_w_body(W, Wt);
}

__global__ __launch_bounds__(256) void pack_w3_kernel(
    const float* __restrict__ Wq, const float* __restrict__ Wk,
    const float* __restrict__ Wv,
    uint32_t* __restrict__ WtQ, uint32_t* __restrict__ WtK,
    uint32_t* __restrict__ WtV)
{
    const float* W; uint32_t* Wt;
    switch (blockIdx.z) {
        case 0:  W = Wq; Wt = WtQ; break;
        case 1:  W = Wk; Wt = WtK; break;
        default: W = Wv; Wt = WtV; break;
    }
    pack_w_body(W, Wt);
}

// ---------------------------------------------------------------------------
// Split-bf16 MFMA GEMM: Y = X(4096,1024) @ W(1024,1024) + bias, 128x128 tile.
// PACK: store packed u32 (hi|lo) output (for attention inputs), else fp32.
// oscale: multiplied into the output (0.125 for Q pre-scaling, exact pow2).
// ---------------------------------------------------------------------------
template <bool SPLIT, bool PACK>
__device__ __forceinline__ void mfma_gemm(const float* __restrict__ X,
                                          const uint32_t* __restrict__ Wt,
                                          const float* __restrict__ bias,
                                          void* __restrict__ Yv,
                                          float oscale)
{
    constexpr int K = 1024;
    __shared__ __align__(16) uint32_t Apk[128][36];

    const int tid  = threadIdx.x;
    const int lane = tid & 63;
    const int wid  = tid >> 6;
    const int wr   = wid >> 1;
    const int wc   = wid & 1;
    const int l15  = lane & 15;
    const int lg   = lane >> 4;

    const int m0 = blockIdx.y * 128;
    const int n0 = blockIdx.x * 128;

    const int sr = tid >> 3;
    const int sk = (tid & 7) * 4;

    const uint32_t* wp[4];
#pragma unroll
    for (int fj = 0; fj < 4; ++fj)
        wp[fj] = Wt + (size_t)(n0 + wc * 64 + fj * 16 + l15) * K + lg * 8;

    f32x4 acc[4][4] = {};

    for (int k0 = 0; k0 < K; k0 += 32) {
        uint4 braw[4][2];
#pragma unroll
        for (int fj = 0; fj < 4; ++fj) {
            braw[fj][0] = *reinterpret_cast<const uint4*>(wp[fj] + k0);
            braw[fj][1] = *reinterpret_cast<const uint4*>(wp[fj] + k0 + 4);
        }

        uint4 apk[4];
#pragma unroll
        for (int i = 0; i < 4; ++i) {
            const float4 xv = *reinterpret_cast<const float4*>(
                &X[(size_t)(m0 + sr + i * 32) * K + k0 + sk]);
            apk[i].x = pack_hl(xv.x);
            apk[i].y = pack_hl(xv.y);
            apk[i].z = pack_hl(xv.z);
            apk[i].w = pack_hl(xv.w);
        }

        __syncthreads();
#pragma unroll
        for (int i = 0; i < 4; ++i)
            *reinterpret_cast<uint4*>(&Apk[sr + i * 32][sk]) = apk[i];
        __syncthreads();

        short8v bhi[4], blo[4];
#pragma unroll
        for (int fj = 0; fj < 4; ++fj)
            unpack_frag(braw[fj][0], braw[fj][1], bhi[fj], blo[fj]);

#pragma unroll
        for (int fi = 0; fi < 4; ++fi) {
            const uint32_t* ap = &Apk[wr * 64 + fi * 16 + l15][lg * 8];
            const uint4 a0 = *reinterpret_cast<const uint4*>(ap);
            const uint4 a1 = *reinterpret_cast<const uint4*>(ap + 4);
            short8v ahi, alo;
            unpack_frag(a0, a1, ahi, alo);
#pragma unroll
            for (int fj = 0; fj < 4; ++fj) {
                acc[fi][fj] = __builtin_amdgcn_mfma_f32_16x16x32_bf16(
                    ahi, bhi[fj], acc[fi][fj], 0, 0, 0);
                acc[fi][fj] = __builtin_amdgcn_mfma_f32_16x16x32_bf16(
                    ahi, blo[fj], acc[fi][fj], 0, 0, 0);
                acc[fi][fj] = __builtin_amdgcn_mfma_f32_16x16x32_bf16(
                    alo, bhi[fj], acc[fi][fj], 0, 0, 0);
            }
        }
    }

#pragma unroll
    for (int fj = 0; fj < 4; ++fj) {
        const int col = n0 + wc * 64 + fj * 16 + l15;
        const float bv = bias[col];
#pragma unroll
        for (int fi = 0; fi < 4; ++fi) {
#pragma unroll
            for (int j = 0; j < 4; ++j) {
                const int row = m0 + wr * 64 + fi * 16 + lg * 4 + j;
                const float val = (acc[fi][fj][j] + bv) * oscale;
                size_t idx;
                if (SPLIT) {
                    const int bb = row >> 11;
                    const int ss = row & 2047;
                    const int hh = col >> 6;
                    const int dd = col & 63;
                    idx = (((size_t)bb * Hn + hh) * Sdim + ss) * DEPTH + dd;
                } else {
                    idx = (size_t)row * Ddim + col;
                }
                if (PACK) ((uint32_t*)Yv)[idx] = pack_hl(val);
                else      ((float*)Yv)[idx]    = val;
            }
        }
    }
}

__global__ __launch_bounds__(256) void proj_kernel(
    const float* __restrict__ q, const float* __restrict__ k,
    const float* __restrict__ v,
    const uint32_t* __restrict__ WtQ, const uint32_t* __restrict__ WtK,
    const uint32_t* __restrict__ WtV,
    const float* __restrict__ bq, const float* __restrict__ bk,
    const float* __restrict__ bv,
    uint32_t* __restrict__ qh, uint32_t* __restrict__ kh,
    uint32_t* __restrict__ vh)
{
    const float* X; const uint32_t* W; const float* bias; uint32_t* Y;
    float sc = 1.0f;
    switch (blockIdx.z) {
        case 0:  X = q; W = WtQ; bias = bq; Y = qh; sc = 0.125f; break;
        case 1:  X = k; W = WtK; bias = bk; Y = kh; break;
        default: X = v; W = WtV; bias = bv; Y = vh; break;
    }
    mfma_gemm<true, true>(X, W, bias, Y, sc);
}

__global__ __launch_bounds__(256) void oproj_kernel(
    const float* __restrict__ ctx, const uint32_t* __restrict__ WtO,
    const float* __restrict__ bo, float* __restrict__ out)
{
    mfma_gemm<false, false>(ctx, WtO, bo, out, 1.0f);
}

// ---------------------------------------------------------------------------
// MFMA attention. One block (4 waves) per 64-row Q-tile per (b,h).
// Pass 1 uses SWAPPED operands: mfma(K, Q) -> S^T (row=k, col=q). Each lane
// then holds 16 k-scores for ONE q (q = l15 of its wave), so the online
// softmax reduce is in-lane + 2 shuffles (xor16, xor32) instead of two
// 4-deep shuffle chains per row. Stats are re-laid out via a 64-float LDS
// exchange for pass 2, which is the unswapped r3 pass (coalesced attn
// stores, P/V via LDS, PV MFMA). XCD-chunked block mapping keeps each
// (b,h)'s K/V L2-resident; heavy (large-qt) tiles dispatch first.
// ---------------------------------------------------------------------------
__global__ __launch_bounds__(256) void attn_mfma_kernel(
    const uint32_t* __restrict__ qpk, const uint32_t* __restrict__ kpk,
    const uint32_t* __restrict__ vpk,
    float* __restrict__ attn, float* __restrict__ ctx)
{
    __shared__ __align__(16) uint32_t Vt[64][68];  // V^T tile: [d][key]
    __shared__ __align__(16) uint32_t Ps[64][68];  // P packed: [qrow][key]
    __shared__ float Msh[64];
    __shared__ float Ssh[64];

    // block mapping: xcd = n&7 keeps all q-tiles of a (b,h) on one XCD
    const int n   = blockIdx.x;
    const int xcd = n & 7;
    const int s   = n >> 3;
    const int c   = ((s >> 5) << 3) | xcd;    // (b,h) combo 0..31
    const int qt  = 31 - (s & 31);            // heavy tiles first
    const int b   = c >> 4;
    const int h   = c & 15;

    const int tid  = threadIdx.x;
    const int lane = tid & 63;
    const int wid  = tid >> 6;
    const int l15  = lane & 15;
    const int lg   = lane >> 4;

    const size_t head = ((size_t)(b * Hn + h)) * Sdim * DEPTH;
    const int q0 = qt * 64;

    const uint32_t* kh_head = kpk + head;
    const uint32_t* vh_head = vpk + head;

    // ---- Q fragments (already scaled by 1/8) hoisted into registers ----
    short8v qhi[2], qlo[2];
    {
        const uint32_t* qp = qpk + head +
            (size_t)(q0 + wid * 16 + l15) * DEPTH + lg * 8;
#pragma unroll
        for (int kk = 0; kk < 2; ++kk) {
            const uint4 r0 = *reinterpret_cast<const uint4*>(qp + kk * 32);
            const uint4 r1 = *reinterpret_cast<const uint4*>(qp + kk * 32 + 4);
            unpack_frag(r0, r1, qhi[kk], qlo[kk]);
        }
    }

    // ---------------- pass 1: stats, swapped mfma(K, Q) ----------------
    // lane state: (m,s) for q = q0 + wid*16 + l15 (replicated across lg)
    float m_s = -INFINITY, s_s = 0.f;
    const int qg_l = q0 + wid * 16 + l15;

    for (int kt = 0; kt <= qt; ++kt) {
        const int k0 = kt * 64;
        f32x4 sacc[4] = {};
#pragma unroll
        for (int fc = 0; fc < 4; ++fc) {
            const uint32_t* p =
                kh_head + (size_t)(k0 + fc * 16 + l15) * DEPTH + lg * 8;
            const uint4 r00 = *reinterpret_cast<const uint4*>(p);
            const uint4 r01 = *reinterpret_cast<const uint4*>(p + 4);
            const uint4 r10 = *reinterpret_cast<const uint4*>(p + 32);
            const uint4 r11 = *reinterpret_cast<const uint4*>(p + 36);
            short8v khi, klo;
            unpack_frag(r00, r01, khi, klo);
            sacc[fc] = __builtin_amdgcn_mfma_f32_16x16x32_bf16(khi, qhi[0], sacc[fc], 0, 0, 0);
            sacc[fc] = __builtin_amdgcn_mfma_f32_16x16x32_bf16(khi, qlo[0], sacc[fc], 0, 0, 0);
            sacc[fc] = __builtin_amdgcn_mfma_f32_16x16x32_bf16(klo, qhi[0], sacc[fc], 0, 0, 0);
            unpack_frag(r10, r11, khi, klo);
            sacc[fc] = __builtin_amdgcn_mfma_f32_16x16x32_bf16(khi, qhi[1], sacc[fc], 0, 0, 0);
            sacc[fc] = __builtin_amdgcn_mfma_f32_16x16x32_bf16(khi, qlo[1], sacc[fc], 0, 0, 0);
            sacc[fc] = __builtin_amdgcn_mfma_f32_16x16x32_bf16(klo, qhi[1], sacc[fc], 0, 0, 0);
        }

        // mask (diag tile only): score row = k index, col = q index
        if (kt == qt) {
#pragma unroll
            for (int fc = 0; fc < 4; ++fc)
#pragma unroll
                for (int j = 0; j < 4; ++j)
                    if (k0 + fc * 16 + lg * 4 + j > qg_l)
                        sacc[fc][j] = -INFINITY;
        }

        // in-lane max over 16, then 2 shuffles across the lg groups
        float tmax = -INFINITY;
#pragma unroll
        for (int fc = 0; fc < 4; ++fc)
#pragma unroll
            for (int j = 0; j < 4; ++j) tmax = fmaxf(tmax, sacc[fc][j]);
        tmax = fmaxf(tmax, __shfl_xor(tmax, 16, 64));
        tmax = fmaxf(tmax, __shfl_xor(tmax, 32, 64));

        const float mnew = fmaxf(m_s, tmax);
        float ps = 0.f;
#pragma unroll
        for (int fc = 0; fc < 4; ++fc)
#pragma unroll
            for (int j = 0; j < 4; ++j) ps += __expf(sacc[fc][j] - mnew);
        ps += __shfl_xor(ps, 16, 64);
        ps += __shfl_xor(ps, 32, 64);

        s_s = s_s * __expf(m_s - mnew) + ps;
        m_s = mnew;
    }

    // redistribute stats to pass-2 layout (q = q0 + wid*16 + lg*4 + j)
    if (lg == 0) { Msh[wid * 16 + l15] = m_s; Ssh[wid * 16 + l15] = s_s; }
    __syncthreads();
    float m_r[4], inv_s[4];
#pragma unroll
    for (int j = 0; j < 4; ++j) {
        m_r[j]   = Msh[wid * 16 + lg * 4 + j];
        inv_s[j] = 1.f / Ssh[wid * 16 + lg * 4 + j];
    }

    f32x4 cacc[4] = {};   // ctx accumulator: [d-frag], rows lg*4+j

    const int vr = tid >> 2;        // V staging: row 0..63
    const int vq = tid & 3;

    // ---------------- pass 2: attn write + PV (unswapped, as r3) --------
    for (int kt = 0; kt <= qt; ++kt) {
        const int k0 = kt * 64;

        // V staging loads (coalesced 64B rows) — issue before compute
        uint4 vraw[4];
#pragma unroll
        for (int i = 0; i < 4; ++i)
            vraw[i] = *reinterpret_cast<const uint4*>(
                vh_head + (size_t)(k0 + vr) * DEPTH + (vq + 4 * i) * 4);

        f32x4 sacc[4] = {};
#pragma unroll
        for (int fc = 0; fc < 4; ++fc) {
            const uint32_t* p =
                kh_head + (size_t)(k0 + fc * 16 + l15) * DEPTH + lg * 8;
            const uint4 r00 = *reinterpret_cast<const uint4*>(p);
            const uint4 r01 = *reinterpret_cast<const uint4*>(p + 4);
            const uint4 r10 = *reinterpret_cast<const uint4*>(p + 32);
            const uint4 r11 = *reinterpret_cast<const uint4*>(p + 36);
            short8v khi, klo;
            unpack_frag(r00, r01, khi, klo);
            sacc[fc] = __builtin_amdgcn_mfma_f32_16x16x32_bf16(qhi[0], khi, sacc[fc], 0, 0, 0);
            sacc[fc] = __builtin_amdgcn_mfma_f32_16x16x32_bf16(qhi[0], klo, sacc[fc], 0, 0, 0);
            sacc[fc] = __builtin_amdgcn_mfma_f32_16x16x32_bf16(qlo[0], khi, sacc[fc], 0, 0, 0);
            unpack_frag(r10, r11, khi, klo);
            sacc[fc] = __builtin_amdgcn_mfma_f32_16x16x32_bf16(qhi[1], khi, sacc[fc], 0, 0, 0);
            sacc[fc] = __builtin_amdgcn_mfma_f32_16x16x32_bf16(qhi[1], klo, sacc[fc], 0, 0, 0);
            sacc[fc] = __builtin_amdgcn_mfma_f32_16x16x32_bf16(qlo[1], khi, sacc[fc], 0, 0, 0);
        }

        const bool diag = (kt == qt);
        uint32_t ppk[4][4];   // [fc][j]
#pragma unroll
        for (int j = 0; j < 4; ++j) {
            const int qg = q0 + wid * 16 + lg * 4 + j;
            float* arow = attn + ((size_t)(b * Hn + h) * Sdim + qg) * Sdim;
#pragma unroll
            for (int fc = 0; fc < 4; ++fc) {
                const int col = k0 + fc * 16 + l15;
                float p = __expf(sacc[fc][j] - m_r[j]) * inv_s[j];
                if (diag && col > qg) p = 0.f;
                arow[col] = p;
                ppk[fc][j] = pack_hl(p);
            }
        }

        __syncthreads();   // prev-tile PV reads of Vt/Ps complete

        // stage V transposed (2-way banks w/ stride-68 pad)
#pragma unroll
        for (int i = 0; i < 4; ++i) {
            const int c0 = (vq + 4 * i) * 4;
            Vt[c0 + 0][vr] = vraw[i].x;
            Vt[c0 + 1][vr] = vraw[i].y;
            Vt[c0 + 2][vr] = vraw[i].z;
            Vt[c0 + 3][vr] = vraw[i].w;
        }
        // stage P packed [qrow][key]
#pragma unroll
        for (int j = 0; j < 4; ++j)
#pragma unroll
            for (int fc = 0; fc < 4; ++fc)
                Ps[wid * 16 + lg * 4 + j][fc * 16 + l15] = ppk[fc][j];

        __syncthreads();

        // PV: ctx += P @ V  (A from Ps rows, B from Vt rows; same slot order)
#pragma unroll
        for (int kk = 0; kk < 2; ++kk) {
            const uint32_t* pap = &Ps[wid * 16 + l15][kk * 32 + lg * 8];
            const uint4 a0 = *reinterpret_cast<const uint4*>(pap);
            const uint4 a1 = *reinterpret_cast<const uint4*>(pap + 4);
            short8v phi, plo;
            unpack_frag(a0, a1, phi, plo);
#pragma unroll
            for (int fc = 0; fc < 4; ++fc) {
                const uint32_t* pbp = &Vt[fc * 16 + l15][kk * 32 + lg * 8];
                const uint4 b0 = *reinterpret_cast<const uint4*>(pbp);
                const uint4 b1 = *reinterpret_cast<const uint4*>(pbp + 4);
                short8v vhi, vlo;
                unpack_frag(b0, b1, vhi, vlo);
                cacc[fc] = __builtin_amdgcn_mfma_f32_16x16x32_bf16(phi, vhi, cacc[fc], 0, 0, 0);
                cacc[fc] = __builtin_amdgcn_mfma_f32_16x16x32_bf16(phi, vlo, cacc[fc], 0, 0, 0);
                cacc[fc] = __builtin_amdgcn_mfma_f32_16x16x32_bf16(plo, vhi, cacc[fc], 0, 0, 0);
            }
        }
    }

    // ctx in concat layout (B, S, D)
#pragma unroll
    for (int fc = 0; fc < 4; ++fc)
#pragma unroll
        for (int j = 0; j < 4; ++j) {
            const int qg = q0 + wid * 16 + lg * 4 + j;
            ctx[((size_t)b * Sdim + qg) * Ddim + h * DEPTH + fc * 16 + l15] =
                cacc[fc][j];
        }
}

// ---------------------------------------------------------------------------
extern "C" void kernel_launch(void* const* d_in, const int* in_sizes, int n_in,
                              void* d_out, int out_size, void* d_ws, size_t ws_size,
                              hipStream_t stream)
{
    (void)in_sizes; (void)n_in; (void)out_size; (void)ws_size;

    const float* v  = (const float*)d_in[0];
    const float* k  = (const float*)d_in[1];
    const float* q  = (const float*)d_in[2];
    const float* Wq = (const float*)d_in[4];
    const float* bq = (const float*)d_in[5];
    const float* Wk = (const float*)d_in[6];
    const float* bk = (const float*)d_in[7];
    const float* Wv = (const float*)d_in[8];
    const float* bv = (const float*)d_in[9];
    const float* Wo = (const float*)d_in[10];
    const float* bo = (const float*)d_in[11];

    float* out  = (float*)d_out;
    float* attn = out + (size_t)Bsz * Sdim * Ddim;

    const size_t sz = (size_t)Bsz * Sdim * Ddim;
    float* ws  = (float*)d_ws;
    uint32_t* qh = (uint32_t*)ws;            // packed hi|lo
    uint32_t* kh = qh + sz;
    uint32_t* vh = kh + sz;
    float*   ctx = (float*)(vh + sz);

    // Weight-pack aliasing (stream-ordered): WtQ/K/V live in the ctx region,
    // consumed by proj before attn writes ctx.  WtO lives in the qh region,
    // packed only after attn has consumed qh.
    uint32_t* WtQ = (uint32_t*)ctx;
    uint32_t* WtK = WtQ + 1024 * 1024;
    uint32_t* WtV = WtK + 1024 * 1024;
    uint32_t* WtO = qh;

    dim3 gpk3(16, 16, 3);
    pack_w3_kernel<<<gpk3, 256, 0, stream>>>(Wq, Wk, Wv, WtQ, WtK, WtV);

    dim3 gproj(Ddim / 128, Mrows / 128, 3);
    proj_kernel<<<gproj, 256, 0, stream>>>(q, k, v, WtQ, WtK, WtV,
                                           bq, bk, bv, qh, kh, vh);

    attn_mfma_kernel<<<dim3(QTILES * Hn * Bsz), 256, 0, stream>>>(
        qh, kh, vh, attn, ctx);

    dim3 gpk(16, 16);
    pack_w_kernel<<<gpk, 256, 0, stream>>>(Wo, WtO);

    dim3 gout(Ddim / 128, Mrows / 128);
    oproj_kernel<<<gout, 256, 0, stream>>>(ctx, WtO, bo, out);
}